// Round 1
// baseline (328.682 us; speedup 1.0000x reference)
//
#include <hip/hip_runtime.h>
#include <math.h>

#define BB 8
#define TT 512
#define CC 8
#define FF 257
#define AA 320
#define EPSF 1e-15f

// ---------------- Workspace layout (floats) ----------------
// xr   : [B][F][C][T]          off 0         size 8421376
// xi   : [B][F][C][T]          off 8421376   size 8421376
// psd_s: [B][F][C][C][2]       off 16842752  size 263168
// psd_n: [B][F][C][C][2]       off 17105920  size 263168
// u    : [B][C]                off 17369088  size 64
// ws   : [B][F][C][2]          off 17369152  size 32896

// K0: transpose (B,T,C,F) -> (B,F,C,T), per-c 32x32 tiles
__global__ __launch_bounds__(256) void k0_transpose(
    const float* __restrict__ dr, const float* __restrict__ di,
    float* __restrict__ xr, float* __restrict__ xi) {
  __shared__ float tr[32][33];
  __shared__ float ti[32][33];
  int bc = blockIdx.z;
  int b = bc >> 3, c = bc & 7;
  int t0 = blockIdx.y * 32;
  int f0 = blockIdx.x * 32;
  int tx = threadIdx.x, ty = threadIdx.y;  // (32,8)
  int f = f0 + tx;
  if (f < FF) {
#pragma unroll
    for (int r = 0; r < 4; ++r) {
      int t = t0 + ty + r * 8;
      size_t idx = ((size_t)(b * TT + t) * CC + c) * FF + f;
      tr[ty + r * 8][tx] = dr[idx];
      ti[ty + r * 8][tx] = di[idx];
    }
  }
  __syncthreads();
  int t = t0 + tx;
#pragma unroll
  for (int r = 0; r < 4; ++r) {
    int ff = f0 + ty + r * 8;
    if (ff < FF) {
      size_t o = ((size_t)(b * FF + ff) * CC + c) * TT + t;
      xr[o] = tr[tx][ty + r * 8];
      xi[o] = ti[tx][ty + r * 8];
    }
  }
}

// K1: per (b,f): normalized masks + both PSDs.
// 256 thr = 4 waves; wave w handles pair-block (c0=(w>>1)*4, e0=(w&1)*4),
// lanes partition t. 4x4 register tile, both masks -> 64 accum floats/thread.
__global__ __launch_bounds__(256) void k1_psd(
    const float* __restrict__ xr, const float* __restrict__ xi,
    const float* __restrict__ mask_s, const float* __restrict__ mask_n,
    float* __restrict__ psd_s, float* __restrict__ psd_n) {
  __shared__ float ms[TT];
  __shared__ float mn[TT];
  __shared__ float scr[4][64][17];  // wave-local reduce scratch (also reused as red[512])
  int bf = blockIdx.x;
  int tid = threadIdx.x;

  // --- mask means over c (coalesced over t) ---
  const float* msk_s = mask_s + (size_t)bf * CC * TT;
  const float* msk_n = mask_n + (size_t)bf * CC * TT;
  for (int t = tid; t < TT; t += 256) {
    float ss = 0.f, sn = 0.f;
#pragma unroll
    for (int c = 0; c < CC; ++c) {
      ss += msk_s[c * TT + t];
      sn += msk_n[c * TT + t];
    }
    ms[t] = ss * (1.0f / CC);
    mn[t] = sn * (1.0f / CC);
  }
  __syncthreads();

  // --- normalize: m /= (sum_t m + EPS) ---
  float* red = &scr[0][0][0];
  red[tid] = ms[tid] + ms[tid + 256];
  red[tid + 256] = mn[tid] + mn[tid + 256];
  __syncthreads();
  for (int s = 128; s > 0; s >>= 1) {
    if (tid < s) {
      red[tid] += red[tid + s];
      red[256 + tid] += red[256 + tid + s];
    }
    __syncthreads();
  }
  float inv_s = 1.0f / (red[0] + EPSF);
  float inv_n = 1.0f / (red[256] + EPSF);
  __syncthreads();
  ms[tid] *= inv_s; ms[tid + 256] *= inv_s;
  mn[tid] *= inv_n; mn[tid + 256] *= inv_n;
  __syncthreads();

  // --- main accumulation ---
  int lane = tid & 63;
  int wv = tid >> 6;
  int cbase = (wv >> 1) * 4;
  int ebase = (wv & 1) * 4;
  const float* xrb = xr + (size_t)bf * CC * TT;
  const float* xib = xi + (size_t)bf * CC * TT;

  float accv[4][16];  // [which*2+comp][i*4+j]
#pragma unroll
  for (int k = 0; k < 4; ++k)
#pragma unroll
    for (int j = 0; j < 16; ++j) accv[k][j] = 0.f;

  for (int it = 0; it < 8; ++it) {
    int t = lane + it * 64;
    float m_s = ms[t], m_n = mn[t];
    float cxr[4], cxi[4], exr[4], exi[4];
#pragma unroll
    for (int i = 0; i < 4; ++i) {
      cxr[i] = xrb[(cbase + i) * TT + t];
      cxi[i] = xib[(cbase + i) * TT + t];
      exr[i] = xrb[(ebase + i) * TT + t];
      exi[i] = xib[(ebase + i) * TT + t];
    }
#pragma unroll
    for (int i = 0; i < 4; ++i)
#pragma unroll
      for (int j = 0; j < 4; ++j) {
        float pre = cxr[i] * exr[j] + cxi[i] * exi[j];
        float pim = cxi[i] * exr[j] - cxr[i] * exi[j];
        accv[0][i * 4 + j] += m_s * pre;
        accv[1][i * 4 + j] += m_s * pim;
        accv[2][i * 4 + j] += m_n * pre;
        accv[3][i * 4 + j] += m_n * pim;
      }
  }

  // --- wave-local reduction over 64 t-lanes, chunked 4x16 ---
  float myval = 0.f;
#pragma unroll
  for (int k = 0; k < 4; ++k) {
    __syncthreads();
#pragma unroll
    for (int j = 0; j < 16; ++j) scr[wv][lane][j] = accv[k][j];
    __syncthreads();
    if ((lane >> 4) == k) {
      int jj = lane & 15;
      float s = 0.f;
      for (int m = 0; m < 64; ++m) s += scr[wv][m][jj];
      myval = s;
    }
  }

  // lane l -> value v=l: which=v>>5, comp=(v>>4)&1, i=(v>>2)&3, j=v&3
  int which = lane >> 5;
  int comp = (lane >> 4) & 1;
  int i = (lane >> 2) & 3;
  int j = lane & 3;
  int c = cbase + i, e = ebase + j;
  size_t o = (((size_t)bf * CC + c) * CC + e) * 2 + comp;
  if (which == 0) psd_s[o] = myval; else psd_n[o] = myval;
}

// K2: attention -> u(B,C). One block per b, 320 threads (thread = a).
__global__ __launch_bounds__(320) void k2_attn(
    const float* __restrict__ psd_s, const float* __restrict__ mlp_w,
    const float* __restrict__ mlp_b, const float* __restrict__ gvec_w,
    const float* __restrict__ gvec_b, float* __restrict__ u) {
  __shared__ float feat[CC][FF];
  __shared__ float cont[CC][321];
  __shared__ float evals[CC];
  int b = blockIdx.x;
  int tid = threadIdx.x;

  // feat[c][f] = | mean_{e!=c} psd_s[b,f,c,e] |
  for (int idx = tid; idx < CC * FF; idx += 320) {
    int c = idx / FF, f = idx - c * FF;
    const float* p = psd_s + (((size_t)b * FF + f) * CC + c) * CC * 2;
    float sre = 0.f, sim = 0.f;
#pragma unroll
    for (int e = 0; e < CC; ++e) {
      if (e == c) continue;
      sre += p[e * 2];
      sim += p[e * 2 + 1];
    }
    sre *= (1.0f / 7.0f);
    sim *= (1.0f / 7.0f);
    feat[c][f] = sqrtf(sre * sre + sim * sim);
  }
  __syncthreads();

  int a = tid;  // 320 == A
  float acc[CC];
  float bb = mlp_b[a];
#pragma unroll
  for (int c = 0; c < CC; ++c) acc[c] = bb;
  for (int f = 0; f < FF; ++f) {
    float w = mlp_w[f * AA + a];
#pragma unroll
    for (int c = 0; c < CC; ++c) acc[c] += feat[c][f] * w;
  }
  float gw = gvec_w[a];
#pragma unroll
  for (int c = 0; c < CC; ++c) cont[c][tid] = tanhf(acc[c]) * gw;
  __syncthreads();
  if (tid < CC) {
    float s = 0.f;
    for (int i2 = 0; i2 < 320; ++i2) s += cont[tid][i2];
    evals[tid] = s;
  }
  __syncthreads();
  if (tid == 0) {
    float gb = gvec_b[0];
    float e[CC], mx = -1e30f;
#pragma unroll
    for (int c = 0; c < CC; ++c) {
      e[c] = 2.0f * (evals[c] + gb);
      mx = fmaxf(mx, e[c]);
    }
    float s = 0.f;
#pragma unroll
    for (int c = 0; c < CC; ++c) {
      e[c] = expf(e[c] - mx);
      s += e[c];
    }
#pragma unroll
    for (int c = 0; c < CC; ++c) u[b * CC + c] = e[c] / s;
  }
}

// K3: per (b,f): Gauss-Jordan solve N X = S (8x16 complex augmented in LDS),
// trace-normalize, contract with u -> ws[b,f,e]. 128 threads: (r,col).
__global__ __launch_bounds__(128) void k3_mvdr(
    const float* __restrict__ psd_s, const float* __restrict__ psd_n,
    const float* __restrict__ u, float* __restrict__ ws) {
  __shared__ float2 aug[8][16];
  __shared__ float2 pinv_sh;
  __shared__ float2 tr_sh;
  int bf = blockIdx.x;
  int b = bf / FF;
  int tid = threadIdx.x;
  int r = tid >> 4, col = tid & 15;

  const float2* Nsrc = (const float2*)(psd_n + (size_t)bf * 128);
  const float2* Ssrc = (const float2*)(psd_s + (size_t)bf * 128);
  aug[r][col] = (col < 8) ? Nsrc[r * 8 + col] : Ssrc[r * 8 + (col - 8)];

  for (int k = 0; k < 8; ++k) {
    __syncthreads();
    if (tid == 0) {
      float2 p = aug[k][k];
      float d = p.x * p.x + p.y * p.y;
      pinv_sh = make_float2(p.x / d, -p.y / d);
    }
    __syncthreads();
    if (r == k) {
      float2 pinv = pinv_sh;
      float2 x = aug[k][col];
      aug[k][col] = make_float2(x.x * pinv.x - x.y * pinv.y,
                                x.x * pinv.y + x.y * pinv.x);
    }
    __syncthreads();
    float2 fac = aug[r][k];
    float2 prow = aug[k][col];
    __syncthreads();
    if (r != k) {
      float2 cur = aug[r][col];
      aug[r][col] = make_float2(cur.x - (fac.x * prow.x - fac.y * prow.y),
                                cur.y - (fac.x * prow.y + fac.y * prow.x));
    }
  }
  __syncthreads();
  if (tid == 0) {
    float txx = 0.f, tyy = 0.f;
#pragma unroll
    for (int c = 0; c < 8; ++c) {
      txx += aug[c][8 + c].x;
      tyy += aug[c][8 + c].y;
    }
    tr_sh = make_float2(txx + EPSF, tyy);
  }
  __syncthreads();
  if (tid < 8) {
    int e = tid;
    float sx = 0.f, sy = 0.f;
#pragma unroll
    for (int c = 0; c < 8; ++c) {
      float uc = u[b * CC + c];
      sx += aug[e][8 + c].x * uc;
      sy += aug[e][8 + c].y * uc;
    }
    float2 tr = tr_sh;
    float d = tr.x * tr.x + tr.y * tr.y;
    float2 w = make_float2((sx * tr.x + sy * tr.y) / d,
                           (sy * tr.x - sx * tr.y) / d);
    ((float2*)ws)[(size_t)bf * 8 + e] = w;
  }
}

// K4: enhanced[b,t,f] = sum_c conj(ws[b,f,c]) * x[b,f,c,t]; out (B,T,F,2).
// One block per (b,t); ws[b] staged in padded LDS; reads original data layout.
__global__ __launch_bounds__(256) void k4_beam(
    const float* __restrict__ dr, const float* __restrict__ di,
    const float* __restrict__ ws, float* __restrict__ out) {
  __shared__ float2 wsp[FF * 9];  // [f][c] stride 9 (bank-conflict-free)
  int bt = blockIdx.x;
  int b = bt / TT;
  int tid = threadIdx.x;
  const float2* wsg = (const float2*)ws + (size_t)b * FF * CC;
  for (int i = tid; i < FF * CC; i += 256) {
    int f = i >> 3, c = i & 7;
    wsp[f * 9 + c] = wsg[i];
  }
  __syncthreads();
  const float* drb = dr + (size_t)bt * (CC * FF);
  const float* dib = di + (size_t)bt * (CC * FF);
  for (int f = tid; f < FF; f += 256) {
    float are = 0.f, aim = 0.f;
#pragma unroll
    for (int c = 0; c < CC; ++c) {
      float xre = drb[c * FF + f];
      float xim = dib[c * FF + f];
      float2 w = wsp[f * 9 + c];
      are += w.x * xre + w.y * xim;   // re(conj(w)*x)
      aim += w.x * xim - w.y * xre;   // im(conj(w)*x)
    }
    ((float2*)out)[(size_t)bt * FF + f] = make_float2(are, aim);
  }
}

extern "C" void kernel_launch(void* const* d_in, const int* in_sizes, int n_in,
                              void* d_out, int out_size, void* d_ws, size_t ws_size,
                              hipStream_t stream) {
  const float* dr = (const float*)d_in[0];
  const float* di = (const float*)d_in[1];
  const float* mask_s = (const float*)d_in[2];
  const float* mask_n = (const float*)d_in[3];
  const float* mlp_w = (const float*)d_in[4];
  const float* mlp_b = (const float*)d_in[5];
  const float* gvec_w = (const float*)d_in[6];
  const float* gvec_b = (const float*)d_in[7];
  float* out = (float*)d_out;

  float* wsf = (float*)d_ws;
  float* xr = wsf;
  float* xi = wsf + 8421376;
  float* psd_s = wsf + 16842752;
  float* psd_n = wsf + 17105920;
  float* uu = wsf + 17369088;
  float* wsv = wsf + 17369152;

  hipLaunchKernelGGL(k0_transpose, dim3(9, 16, BB * CC), dim3(32, 8), 0, stream,
                     dr, di, xr, xi);
  hipLaunchKernelGGL(k1_psd, dim3(BB * FF), dim3(256), 0, stream,
                     xr, xi, mask_s, mask_n, psd_s, psd_n);
  hipLaunchKernelGGL(k2_attn, dim3(BB), dim3(320), 0, stream,
                     psd_s, mlp_w, mlp_b, gvec_w, gvec_b, uu);
  hipLaunchKernelGGL(k3_mvdr, dim3(BB * FF), dim3(128), 0, stream,
                     psd_s, psd_n, uu, wsv);
  hipLaunchKernelGGL(k4_beam, dim3(BB * TT), dim3(256), 0, stream,
                     dr, di, wsv, out);
}

// Round 2
// 270.030 us; speedup vs baseline: 1.2172x; 1.2172x over previous
//
#include <hip/hip_runtime.h>
#include <math.h>

#define TTOT 512
#define CCH 8
#define FFR 257
#define AAH 320
#define NBF 2056      // B*F
#define BF2 2112      // padded to 33*64
#define NTIL 16       // t tiles in k_psd grid
#define EPSF 1e-15f
#define WSB (FFR * 8) // ws complex elements per b

// ---------------- workspace layout (floats) ----------------
#define OFF_MBAR 0                              // [2][512][BF2]
#define SZ_MBAR (2 * 512 * BF2)
#define OFF_PART (OFF_MBAR + SZ_MBAR)           // [144][NTIL][BF2]
#define SZ_PART (144 * NTIL * BF2)
#define OFF_PSDS (OFF_PART + SZ_PART)           // [NBF][8][8][2]
#define SZ_PSD (NBF * 128)
#define OFF_PSDN (OFF_PSDS + SZ_PSD)
#define OFF_E (OFF_PSDN + SZ_PSD)               // [64]
#define OFF_WS (OFF_E + 64)                     // [NBF][8][2]

__device__ __constant__ int c_pi[36] = {0,0,0,0,0,0,0,0, 1,1,1,1,1,1,1, 2,2,2,2,2,2,
                                        3,3,3,3,3, 4,4,4,4, 5,5,5, 6,6, 7};
__device__ __constant__ int c_pj[36] = {0,1,2,3,4,5,6,7, 1,2,3,4,5,6,7, 2,3,4,5,6,7,
                                        3,4,5,6,7, 4,5,6,7, 5,6,7, 6,7, 7};

// K_mask: per (b,f): m = mean_c(mask); m /= (sum_t m + EPS). Write [mask][t][bf].
__global__ __launch_bounds__(256) void k_mask(
    const float* __restrict__ mask_s, const float* __restrict__ mask_n,
    float* __restrict__ mbar) {
  int bf = blockIdx.x;
  int tid = threadIdx.x;
  int lane = tid & 63, wv = tid >> 6;
  const float2* ms = (const float2*)(mask_s + (size_t)bf * CCH * TTOT);
  const float2* mn = (const float2*)(mask_n + (size_t)bf * CCH * TTOT);
  float2 ss = make_float2(0.f, 0.f), sn = make_float2(0.f, 0.f);
#pragma unroll
  for (int c = 0; c < 8; ++c) {
    float2 a = ms[c * 256 + tid];
    ss.x += a.x; ss.y += a.y;
    float2 b = mn[c * 256 + tid];
    sn.x += b.x; sn.y += b.y;
  }
  float tots = ss.x + ss.y, totn = sn.x + sn.y;
#pragma unroll
  for (int off = 32; off > 0; off >>= 1) {
    tots += __shfl_down(tots, off);
    totn += __shfl_down(totn, off);
  }
  __shared__ float reds[4], redn[4];
  if (lane == 0) { reds[wv] = tots; redn[wv] = totn; }
  __syncthreads();
  float totS = reds[0] + reds[1] + reds[2] + reds[3];
  float totN = redn[0] + redn[1] + redn[2] + redn[3];
  float invs = 1.f / (totS * 0.125f + EPSF);
  float invn = 1.f / (totN * 0.125f + EPSF);
  int t0 = 2 * tid;
  mbar[(size_t)t0 * BF2 + bf] = ss.x * 0.125f * invs;
  mbar[(size_t)(t0 + 1) * BF2 + bf] = ss.y * 0.125f * invs;
  mbar[(size_t)(512 + t0) * BF2 + bf] = sn.x * 0.125f * invn;
  mbar[(size_t)(512 + t0 + 1) * BF2 + bf] = sn.y * 0.125f * invn;
}

// K_psd: lane=(b,f) reads original (B,T,C,F) layout coalesced over f; 36 Hermitian
// pairs x {s,n} x {re,im} in registers; wave = t-subgroup; grid (33, NTIL).
__global__ __launch_bounds__(256) void k_psd(
    const float* __restrict__ dr, const float* __restrict__ di,
    const float* __restrict__ mbar, float* __restrict__ partial) {
  int lane = threadIdx.x & 63, wv = threadIdx.x >> 6;
  int bfb = blockIdx.x;
  int ttile = blockIdx.y;
  int bf = bfb * 64 + lane;
  if (bf > NBF - 1) bf = NBF - 1;
  int b = bf / FFR, f = bf - b * FFR;
  size_t dbase = (size_t)b * TTOT * CCH * FFR + f;
  int t0 = ttile * 32 + wv * 8;

  float acc[36][4];
#pragma unroll
  for (int p = 0; p < 36; ++p) {
    acc[p][0] = 0.f; acc[p][1] = 0.f; acc[p][2] = 0.f; acc[p][3] = 0.f;
  }

  for (int tt = 0; tt < 8; ++tt) {
    int t = t0 + tt;
    const float* pr = dr + dbase + (size_t)t * (CCH * FFR);
    const float* pi = di + dbase + (size_t)t * (CCH * FFR);
    float xre[8], xim[8];
#pragma unroll
    for (int c = 0; c < 8; ++c) { xre[c] = pr[c * FFR]; xim[c] = pi[c * FFR]; }
    float m_s = mbar[(size_t)t * BF2 + bf];
    float m_n = mbar[(size_t)(512 + t) * BF2 + bf];
    int p = 0;
#pragma unroll
    for (int i = 0; i < 8; ++i)
#pragma unroll
      for (int j = i; j < 8; ++j) {
        float pre = xre[i] * xre[j] + xim[i] * xim[j];
        float pim = xim[i] * xre[j] - xre[i] * xim[j];
        acc[p][0] += m_s * pre; acc[p][1] += m_s * pim;
        acc[p][2] += m_n * pre; acc[p][3] += m_n * pim;
        ++p;
      }
  }

  __shared__ float scr[4][36][65];
#pragma unroll
  for (int r = 0; r < 4; ++r) {
    if (r) __syncthreads();
#pragma unroll
    for (int pp = 0; pp < 9; ++pp)
#pragma unroll
      for (int mc = 0; mc < 4; ++mc)
        scr[wv][pp * 4 + mc][lane] = acc[r * 9 + pp][mc];
    __syncthreads();
#pragma unroll
    for (int k = 0; k < 9; ++k) {
      int v = wv * 9 + k;
      float s = scr[0][v][lane] + scr[1][v][lane] + scr[2][v][lane] + scr[3][v][lane];
      int g = r * 36 + v;  // == pair*4 + mc
      partial[((size_t)g * NTIL + ttile) * BF2 + bfb * 64 + lane] = s;
    }
  }
}

// K_reduce: sum partials over NTIL, expand Hermitian, write psd_s/psd_n.
__global__ __launch_bounds__(256) void k_reduce(
    const float* __restrict__ partial, float* __restrict__ psd_s,
    float* __restrict__ psd_n) {
  int lane = threadIdx.x & 63, wv = threadIdx.x >> 6;
  int bf = blockIdx.x * 64 + lane;
  float vals[9][4];
#pragma unroll
  for (int pp = 0; pp < 9; ++pp)
#pragma unroll
    for (int mc = 0; mc < 4; ++mc) {
      int g = (wv * 9 + pp) * 4 + mc;
      const float* src = partial + (size_t)g * NTIL * BF2 + blockIdx.x * 64 + lane;
      float s = 0.f;
#pragma unroll
      for (int nt = 0; nt < NTIL; ++nt) s += src[nt * BF2];
      vals[pp][mc] = s;
    }
  if (bf < NBF) {
    size_t base = (size_t)bf * 128;
#pragma unroll
    for (int pp = 0; pp < 9; ++pp) {
      int p = wv * 9 + pp;
      int i = c_pi[p], j = c_pj[p];
      float sre = vals[pp][0], sim = vals[pp][1];
      float nre = vals[pp][2], nim = vals[pp][3];
      psd_s[base + (i * 8 + j) * 2] = sre;
      psd_s[base + (i * 8 + j) * 2 + 1] = sim;
      psd_s[base + (j * 8 + i) * 2] = sre;
      psd_s[base + (j * 8 + i) * 2 + 1] = -sim;
      psd_n[base + (i * 8 + j) * 2] = nre;
      psd_n[base + (i * 8 + j) * 2 + 1] = nim;
      psd_n[base + (j * 8 + i) * 2] = nre;
      psd_n[base + (j * 8 + i) * 2 + 1] = -nim;
    }
  }
}

// K2: block per (b,c): feat -> MLP -> tanh -> gvec -> block reduce -> e[b*8+c].
__global__ __launch_bounds__(320) void k2_attn(
    const float* __restrict__ psd_s, const float* __restrict__ mlp_w,
    const float* __restrict__ mlp_b, const float* __restrict__ gvec_w,
    float* __restrict__ e_out) {
  __shared__ float feat[FFR];
  __shared__ float wred[5];
  int bx = blockIdx.x;
  int b = bx >> 3, c = bx & 7;
  int tid = threadIdx.x;
  int lane = tid & 63, wv = tid >> 6;
  if (tid < FFR) {
    const float* p = psd_s + (((size_t)(b * FFR + tid)) * 8 + c) * 16;
    float sre = 0.f, sim = 0.f;
#pragma unroll
    for (int e = 0; e < 8; ++e) {
      if (e != c) { sre += p[e * 2]; sim += p[e * 2 + 1]; }
    }
    sre *= (1.0f / 7.0f);
    sim *= (1.0f / 7.0f);
    feat[tid] = sqrtf(sre * sre + sim * sim);
  }
  __syncthreads();
  float acc = mlp_b[tid];
  for (int f = 0; f < FFR; ++f) acc += feat[f] * mlp_w[f * AAH + tid];
  float v = tanhf(acc) * gvec_w[tid];
#pragma unroll
  for (int off = 32; off > 0; off >>= 1) v += __shfl_down(v, off);
  if (lane == 0) wred[wv] = v;
  __syncthreads();
  if (tid == 0) e_out[bx] = wred[0] + wred[1] + wred[2] + wred[3] + wred[4];
}

// K3: one wave per (b,f); barrier-free Gauss-Jordan via shuffles; fused softmax.
__global__ __launch_bounds__(256) void k3_mvdr(
    const float* __restrict__ psd_s, const float* __restrict__ psd_n,
    const float* __restrict__ e_in, const float* __restrict__ gvec_b,
    float* __restrict__ ws) {
  int lane = threadIdx.x & 63, wv = threadIdx.x >> 6;
  int bf = blockIdx.x * 4 + wv;  // 514*4 == 2056 exact
  int b = bf / FFR;
  int r = lane >> 3, c = lane & 7;
  float2 n = ((const float2*)(psd_n + (size_t)bf * 128))[lane];
  float2 s = ((const float2*)(psd_s + (size_t)bf * 128))[lane];

#pragma unroll
  for (int k = 0; k < 8; ++k) {
    float pvre = __shfl(n.x, k * 9), pvim = __shfl(n.y, k * 9);
    float dinv = 1.f / (pvre * pvre + pvim * pvim);
    float pire = pvre * dinv, piim = -pvim * dinv;
    if (r == k) {
      float2 nn = n, ss = s;
      n.x = nn.x * pire - nn.y * piim; n.y = nn.x * piim + nn.y * pire;
      s.x = ss.x * pire - ss.y * piim; s.y = ss.x * piim + ss.y * pire;
    }
    float fre = __shfl(n.x, r * 8 + k), fim = __shfl(n.y, r * 8 + k);
    float pnre = __shfl(n.x, k * 8 + c), pnim = __shfl(n.y, k * 8 + c);
    float psre = __shfl(s.x, k * 8 + c), psim = __shfl(s.y, k * 8 + c);
    if (r != k) {
      n.x -= fre * pnre - fim * pnim; n.y -= fre * pnim + fim * pnre;
      s.x -= fre * psre - fim * psim; s.y -= fre * psim + fim * psre;
    }
  }
  float trx = (r == c) ? s.x : 0.f, tryy = (r == c) ? s.y : 0.f;
#pragma unroll
  for (int off = 1; off < 64; off <<= 1) {
    trx += __shfl_xor(trx, off);
    tryy += __shfl_xor(tryy, off);
  }
  float val = 2.f * (e_in[b * 8 + c] + gvec_b[0]);
  float mx = val;
#pragma unroll
  for (int off = 1; off < 8; off <<= 1) mx = fmaxf(mx, __shfl_xor(mx, off));
  float pe = expf(val - mx);
  float psum = pe;
#pragma unroll
  for (int off = 1; off < 8; off <<= 1) psum += __shfl_xor(psum, off);
  float uc = pe / psum;
  float wre = s.x * uc, wim = s.y * uc;
#pragma unroll
  for (int off = 1; off < 8; off <<= 1) {
    wre += __shfl_xor(wre, off);
    wim += __shfl_xor(wim, off);
  }
  float tre = trx + EPSF, tim = tryy;
  float d2 = 1.f / (tre * tre + tim * tim);
  float owre = (wre * tre + wim * tim) * d2;
  float owim = (wim * tre - wre * tim) * d2;
  if (c == 0) ((float2*)ws)[(size_t)bf * 8 + r] = make_float2(owre, owim);
}

// K4: block = (b, 4-t tile); stage ws[b] in padded LDS; coalesced f reads.
__global__ __launch_bounds__(256) void k4_beam(
    const float* __restrict__ dr, const float* __restrict__ di,
    const float* __restrict__ ws, float* __restrict__ out) {
  __shared__ float2 wsp[FFR * 9];
  int b = blockIdx.y;
  int t0 = blockIdx.x * 4;
  int tid = threadIdx.x;
  const float2* wsg = (const float2*)ws + (size_t)b * WSB;
  for (int i = tid; i < FFR * 8; i += 256) {
    int f = i >> 3, c = i & 7;
    wsp[f * 9 + c] = wsg[i];
  }
  __syncthreads();
  for (int ts = 0; ts < 4; ++ts) {
    int t = t0 + ts;
    const float* drb = dr + (size_t)(b * TTOT + t) * (CCH * FFR);
    const float* dib = di + (size_t)(b * TTOT + t) * (CCH * FFR);
    for (int f = tid; f < FFR; f += 256) {
      float are = 0.f, aim = 0.f;
#pragma unroll
      for (int c = 0; c < 8; ++c) {
        float xre = drb[c * FFR + f];
        float xim = dib[c * FFR + f];
        float2 w = wsp[f * 9 + c];
        are += w.x * xre + w.y * xim;
        aim += w.x * xim - w.y * xre;
      }
      ((float2*)out)[(size_t)(b * TTOT + t) * FFR + f] = make_float2(are, aim);
    }
  }
}

extern "C" void kernel_launch(void* const* d_in, const int* in_sizes, int n_in,
                              void* d_out, int out_size, void* d_ws, size_t ws_size,
                              hipStream_t stream) {
  const float* dr = (const float*)d_in[0];
  const float* di = (const float*)d_in[1];
  const float* mask_s = (const float*)d_in[2];
  const float* mask_n = (const float*)d_in[3];
  const float* mlp_w = (const float*)d_in[4];
  const float* mlp_b = (const float*)d_in[5];
  const float* gvec_w = (const float*)d_in[6];
  const float* gvec_b = (const float*)d_in[7];
  float* out = (float*)d_out;

  float* wsf = (float*)d_ws;
  float* mbar = wsf + OFF_MBAR;
  float* part = wsf + OFF_PART;
  float* psd_s = wsf + OFF_PSDS;
  float* psd_n = wsf + OFF_PSDN;
  float* e_arr = wsf + OFF_E;
  float* wsv = wsf + OFF_WS;

  hipLaunchKernelGGL(k_mask, dim3(NBF), dim3(256), 0, stream, mask_s, mask_n, mbar);
  hipLaunchKernelGGL(k_psd, dim3(33, NTIL), dim3(256), 0, stream, dr, di, mbar, part);
  hipLaunchKernelGGL(k_reduce, dim3(33), dim3(256), 0, stream, part, psd_s, psd_n);
  hipLaunchKernelGGL(k2_attn, dim3(64), dim3(320), 0, stream,
                     psd_s, mlp_w, mlp_b, gvec_w, e_arr);
  hipLaunchKernelGGL(k3_mvdr, dim3(514), dim3(256), 0, stream,
                     psd_s, psd_n, e_arr, gvec_b, wsv);
  hipLaunchKernelGGL(k4_beam, dim3(128, 8), dim3(256), 0, stream, dr, di, wsv, out);
}